// Round 2
// baseline (585.043 us; speedup 1.0000x reference)
//
#include <hip/hip_runtime.h>
#include <hip/hip_bf16.h>
#include <math.h>

#define B_ 2
#define L_ 2048
#define D_ 1024
#define H_ 4
#define NC 64   // chunks per sequence

typedef unsigned short ushort_t;
typedef __bf16 bf16x8 __attribute__((ext_vector_type(8)));
typedef float f32x4 __attribute__((ext_vector_type(4)));
typedef ushort_t u16x8 __attribute__((ext_vector_type(8)));

__device__ __forceinline__ ushort_t f2bs(float f) {
    __hip_bfloat16 h = __float2bfloat16(f);
    ushort_t u;
    __builtin_memcpy(&u, &h, 2);
    return u;
}

__device__ __forceinline__ float wred(float v) {
    v += __shfl_down(v, 32);
    v += __shfl_down(v, 16);
    v += __shfl_down(v, 8);
    v += __shfl_down(v, 4);
    v += __shfl_down(v, 2);
    v += __shfl_down(v, 1);
    return v;
}

__device__ __forceinline__ void gload16(const void* g, void* l) {
    __builtin_amdgcn_global_load_lds((const __attribute__((address_space(1))) void*)g,
                                     (__attribute__((address_space(3))) void*)l, 16, 0, 0);
}

// ------------------------------------------- transpose+cast: W[K][N] f32 -> WT[N][K] bf16
__global__ __launch_bounds__(256) void tcast_k(const float* __restrict__ W,
                                               ushort_t* __restrict__ WT, int K, int N) {
    __shared__ float tile[32 * 33];
    const int k0 = blockIdx.y << 5, n0 = blockIdx.x << 5;
    for (int e = threadIdx.x; e < 1024; e += 256)
        tile[(e >> 5) * 33 + (e & 31)] = W[(size_t)(k0 + (e >> 5)) * N + n0 + (e & 31)];
    __syncthreads();
    for (int e = threadIdx.x; e < 1024; e += 256)
        WT[(size_t)(n0 + (e >> 5)) * K + k0 + (e & 31)] = f2bs(tile[(e & 31) * 33 + (e >> 5)]);
}

// ------------------------------------------- cast f32 -> bf16 flat
__global__ __launch_bounds__(256) void cast_k(const float* __restrict__ x,
                                              ushort_t* __restrict__ y) {
    const int i = blockIdx.x * 256 + threadIdx.x;
    const float4 v = *(const float4*)&x[(size_t)i * 4];
    ushort4 p;
    p.x = f2bs(v.x); p.y = f2bs(v.y); p.z = f2bs(v.z); p.w = f2bs(v.w);
    *(ushort4*)&y[(size_t)i * 4] = p;
}

// ------------------------------------------- bf16 MFMA GEMM (TN): C = act(A @ Bt^T + bias)
template <int ACT>
__global__ __launch_bounds__(256) void gemm_bf(const ushort_t* __restrict__ A,
                                               const ushort_t* __restrict__ Bt,
                                               const float* __restrict__ bias,
                                               float* __restrict__ C,
                                               int M, int N, int K) {
    __shared__ ushort_t As[128 * 32];
    __shared__ ushort_t Bs[128 * 32];
    const int t = threadIdx.x;
    const int wv = t >> 6, l = t & 63;
    const int m0 = blockIdx.y << 7, n0 = blockIdx.x << 7;
    const int wm = wv & 1, wn = wv >> 1;
    const int q4 = l >> 4, c16 = l & 15;
    f32x4 acc[4][4];
#pragma unroll
    for (int i = 0; i < 4; ++i)
#pragma unroll
        for (int j = 0; j < 4; ++j) {
            f32x4 z = {0.f, 0.f, 0.f, 0.f};
            acc[i][j] = z;
        }
    const int srow = (l >> 2);
    const int scol = (l & 3) << 3;
    for (int k0 = 0; k0 < K; k0 += 32) {
        __syncthreads();
#pragma unroll
        for (int si = 0; si < 2; ++si) {
            const int s = wv * 2 + si;
            gload16(&A[(size_t)(m0 + s * 16 + srow) * K + k0 + scol], &As[s * 512]);
            gload16(&Bt[(size_t)(n0 + s * 16 + srow) * K + k0 + scol], &Bs[s * 512]);
        }
        __syncthreads();
        bf16x8 af[4], bff[4];
#pragma unroll
        for (int mi = 0; mi < 4; ++mi)
            af[mi] = *(const bf16x8*)&As[(wm * 64 + mi * 16 + c16) * 32 + q4 * 8];
#pragma unroll
        for (int ni = 0; ni < 4; ++ni)
            bff[ni] = *(const bf16x8*)&Bs[(wn * 64 + ni * 16 + c16) * 32 + q4 * 8];
#pragma unroll
        for (int mi = 0; mi < 4; ++mi)
#pragma unroll
            for (int ni = 0; ni < 4; ++ni)
                acc[mi][ni] = __builtin_amdgcn_mfma_f32_16x16x32_bf16(af[mi], bff[ni],
                                                                     acc[mi][ni], 0, 0, 0);
    }
#pragma unroll
    for (int mi = 0; mi < 4; ++mi)
#pragma unroll
        for (int ni = 0; ni < 4; ++ni)
#pragma unroll
            for (int r = 0; r < 4; ++r) {
                const int row = m0 + wm * 64 + mi * 16 + q4 * 4 + r;
                const int col = n0 + wn * 64 + ni * 16 + c16;
                float v = acc[mi][ni][r];
                if (ACT == 1) {
                    v += bias[col];
                    v = 0.5f * v * (1.0f + erff(v * 0.70710678118654752f));
                }
                C[(size_t)row * N + col] = v;
            }
}

// ---------------- fused causal conv(K=4) + silu (+ row l2norm), LDS-tiled
template <int DO_NORM, int EMIT_F32, int EMIT_BF>
__global__ __launch_bounds__(256) void convql_k(const float* __restrict__ X,
                                                const float* __restrict__ cw,
                                                float* __restrict__ Y,
                                                ushort_t* __restrict__ Ybf) {
    __shared__ float xs[35 * 256];
    const int bid = blockIdx.x;
    const int h = bid & 3, lt = (bid >> 2) & 63, b = bid >> 8;
    const int t = threadIdx.x;
    const int l0 = lt << 5;
    const int cg = (h << 8) | t;
    for (int e = t; e < 35 * 256; e += 256) {
        const int r = e >> 8, c = e & 255;
        const int gl = l0 + r - 3;
        xs[e] = (gl >= 0) ? X[((size_t)(b * L_) + gl) * 3072 + (h << 8) + c] : 0.f;
    }
    const float w0 = cw[cg * 4 + 0], w1 = cw[cg * 4 + 1];
    const float w2 = cw[cg * 4 + 2], w3 = cw[cg * 4 + 3];
    __syncthreads();
    float yr[32];
#pragma unroll
    for (int l = 0; l < 32; ++l) {
        const float a = xs[(l + 0) * 256 + t] * w0 + xs[(l + 1) * 256 + t] * w1 +
                        xs[(l + 2) * 256 + t] * w2 + xs[(l + 3) * 256 + t] * w3;
        yr[l] = a / (1.f + expf(-a));
    }
    if (DO_NORM) {
        __syncthreads();
#pragma unroll
        for (int l = 0; l < 32; ++l) xs[l * 256 + t] = yr[l];
        __syncthreads();
        const int wv = t >> 6, lane = t & 63;
#pragma unroll
        for (int ri = 0; ri < 8; ++ri) {
            const int r = wv * 8 + ri;
            float4 v = *(float4*)&xs[r * 256 + lane * 4];
            float ss = v.x * v.x + v.y * v.y + v.z * v.z + v.w * v.w;
            ss = wred(ss);
            ss = __shfl(ss, 0);
            const float s = rsqrtf(ss + 1e-6f);
            v.x *= s; v.y *= s; v.z *= s; v.w *= s;
            const size_t go = ((size_t)(b * L_) + l0 + r) * 1024 + (h << 8) + lane * 4;
            if (EMIT_F32) *(float4*)&Y[go] = v;
            if (EMIT_BF) {
                ushort4 p;
                p.x = f2bs(v.x); p.y = f2bs(v.y); p.z = f2bs(v.z); p.w = f2bs(v.w);
                *(ushort4*)&Ybf[go] = p;
            }
        }
    } else {
#pragma unroll
        for (int l = 0; l < 32; ++l)
            if (EMIT_F32) Y[((size_t)(b * L_) + l0 + l) * 1024 + cg] = yr[l];
    }
}

// ---------------- fused FIR branches (K=1,3,7,31), LDS-tiled, one read of v
__global__ __launch_bounds__(256) void fir_k(const float* __restrict__ V,
                                             const float* __restrict__ w1w,
                                             const float* __restrict__ w3w,
                                             const float* __restrict__ w7w,
                                             const float* __restrict__ w31w,
                                             float* __restrict__ o1,
                                             float* __restrict__ o3,
                                             float* __restrict__ o7,
                                             float* __restrict__ o31) {
    __shared__ float xs[62 * 256];
    const int bid = blockIdx.x;
    const int h = bid & 3, lt = (bid >> 2) & 63, b = bid >> 8;
    const int t = threadIdx.x;
    const int l0 = lt << 5;
    const int cg = (h << 8) | t;
    for (int e = t; e < 62 * 256; e += 256) {
        const int r = e >> 8, c = e & 255;
        const int gl = l0 + r - 30;
        xs[e] = (gl >= 0) ? V[((size_t)(b * L_) + gl) * 1024 + (h << 8) + c] : 0.f;
    }
    float lw31[31], lw7[7], lw3[3];
#pragma unroll
    for (int j = 0; j < 31; ++j) lw31[j] = w31w[cg * 31 + j];
#pragma unroll
    for (int j = 0; j < 7; ++j) lw7[j] = w7w[cg * 7 + j];
#pragma unroll
    for (int j = 0; j < 3; ++j) lw3[j] = w3w[cg * 3 + j];
    const float lw1 = w1w[cg];
    __syncthreads();
    for (int l = 0; l < 32; ++l) {
        float a31 = 0.f, a7 = 0.f, a3 = 0.f, v = 0.f;
#pragma unroll
        for (int j = 0; j < 31; ++j) {
            v = xs[(l + j) * 256 + t];
            a31 += v * lw31[j];
            if (j >= 24) a7 += v * lw7[j - 24];
            if (j >= 28) a3 += v * lw3[j - 28];
        }
        const size_t go = ((size_t)(b * L_) + l0 + l) * 1024 + cg;
        o31[go] = a31;
        o7[go] = a7;
        o3[go] = a3;
        o1[go] = v * lw1;
    }
}

// ------------------- beta = sigmoid(hs @ b_w); also emit gate_in hs-part (bf16)
__global__ __launch_bounds__(64) void beta_k(const float* __restrict__ hs,
                                             const float* __restrict__ bw,
                                             float* __restrict__ beta,
                                             ushort_t* __restrict__ gin) {
    const int row = blockIdx.x;
    const int lane = threadIdx.x;
    float a0 = 0, a1 = 0, a2 = 0, a3 = 0;
    const float* hp = hs + (size_t)row * D_;
    ushort_t* gp = gin + (size_t)row * 1120;
    for (int c = lane; c < D_; c += 64) {
        const float x = hp[c];
        gp[c] = f2bs(x);
        a0 += x * bw[c * 4 + 0];
        a1 += x * bw[c * 4 + 1];
        a2 += x * bw[c * 4 + 2];
        a3 += x * bw[c * 4 + 3];
    }
    a0 = wred(a0); a1 = wred(a1); a2 = wred(a2); a3 = wred(a3);
    if (lane == 0) {
        float* o = beta + (size_t)row * 4;
        o[0] = 1.f / (1.f + expf(-a0));
        o[1] = 1.f / (1.f + expf(-a1));
        o[2] = 1.f / (1.f + expf(-a2));
        o[3] = 1.f / (1.f + expf(-a3));
    }
}

// --------------- fused MFMA delta-prep. Exports ALL scan operands in
// MFMA-fragment-linear layouts (coalesced 16B/lane reads in the scan):
//   qfr/wfr[((cb*2+wv)*8+s)*512 + lane*8]   (A-frags, rows wv*16+l16)
//   atfr[(cb*2+wv)*512 + lane*8]            (attn A-frag)
//   ktfr[(cb*16+tc)*512 + lane*8]           (kT A-frag per c-tile)
//   ufr[((cb*16+nt)*2+mi)*256 + lane*4]     (fp32 C-layout slices)
__global__ __launch_bounds__(256) void prep2_k(const ushort_t* __restrict__ qbf,
                                               const ushort_t* __restrict__ kbf,
                                               const float* __restrict__ vg,
                                               const float* __restrict__ beta,
                                               ushort_t* __restrict__ qfr,
                                               ushort_t* __restrict__ wfr,
                                               float* __restrict__ ufr,
                                               ushort_t* __restrict__ atfr,
                                               ushort_t* __restrict__ ktfr) {
    __shared__ ushort_t k_lds[32 * 264];   // k rows; reused as w_s later
    __shared__ ushort_t kT_lds[256 * 32];  // swizzled: seg s at (s ^ ((c>>1)&3))
    __shared__ ushort_t vT_lds[256 * 32];  // same swizzle
    __shared__ float Am[32 * 33];
    __shared__ float Tm[32 * 33];
    __shared__ ushort_t Tb[32 * 40];       // T' bf16
    __shared__ ushort_t at_s[32 * 40];     // attn bf16 (row-major, 16B-aligned rows)
    __shared__ float beta_s[32];
    const int bid = blockIdx.x;  // bh*NC + ci
    const int bh = bid >> 6, ci = bid & 63;
    const int b = bh >> 2, h = bh & 3;
    const int t = threadIdx.x;
    const int wv = t >> 6, lane = t & 63;
    const int mi = wv & 1, ni = wv >> 1;
    const int l16 = lane & 15, quad = lane >> 4;
    const size_t cb = (size_t)bid;
    const size_t grow = ((size_t)(b * L_ + ci * 32)) * 1024 + (h << 8);
    const f32x4 z4 = {0.f, 0.f, 0.f, 0.f};

    if (t < 32) beta_s[t] = beta[(size_t)(b * L_ + ci * 32 + t) * 4 + h];
    // stage k rows (plain, padded)
#pragma unroll
    for (int j = 0; j < 4; ++j) {
        const int idx = j * 2048 + t * 8, r = idx >> 8, c = idx & 255;
        *(u16x8*)&k_lds[r * 264 + c] = *(const u16x8*)&kbf[grow + (size_t)r * 1024 + c];
    }
    // build vT (bf16, swizzled) from global v
#pragma unroll
    for (int j = 0; j < 8; ++j) {
        const int e = j * 1024 + t * 4, r = e >> 8, c = e & 255;
        const float4 v4 = *(const float4*)&vg[grow + (size_t)r * 1024 + c];
        const float vv[4] = {v4.x, v4.y, v4.z, v4.w};
#pragma unroll
        for (int x = 0; x < 4; ++x) {
            const int cc = c + x;
            const int sp = (r >> 3) ^ ((cc >> 1) & 3);
            vT_lds[cc * 32 + sp * 8 + (r & 7)] = f2bs(vv[x]);
        }
    }
    // G = k@kT and attn = q@kT from global register fragments; waves 0,1 export qfr
    f32x4 g = z4, atv = z4;
#pragma unroll
    for (int s = 0; s < 8; ++s) {
        const bf16x8 a =
            *(const bf16x8*)&kbf[grow + (size_t)(mi * 16 + l16) * 1024 + s * 32 + (quad << 3)];
        const bf16x8 bb =
            *(const bf16x8*)&kbf[grow + (size_t)(ni * 16 + l16) * 1024 + s * 32 + (quad << 3)];
        const bf16x8 qa =
            *(const bf16x8*)&qbf[grow + (size_t)(mi * 16 + l16) * 1024 + s * 32 + (quad << 3)];
        g = __builtin_amdgcn_mfma_f32_16x16x32_bf16(a, bb, g, 0, 0, 0);
        atv = __builtin_amdgcn_mfma_f32_16x16x32_bf16(qa, bb, atv, 0, 0, 0);
        if (ni == 0) *(bf16x8*)&qfr[((cb * 2 + mi) * 8 + s) * 512 + lane * 8] = qa;
    }
    __syncthreads();  // beta_s + k_lds + vT visible
    // Am / Tm init + attn -> at_s
#pragma unroll
    for (int r = 0; r < 4; ++r) {
        const int row = mi * 16 + (quad << 2) + r;
        const int col = ni * 16 + l16;
        Am[row * 33 + col] = (col < row) ? -beta_s[row] * g[r] : 0.f;
        Tm[row * 33 + col] = (row == col) ? 1.f : 0.f;
        at_s[row * 40 + col] = (col <= row) ? f2bs(atv[r]) : (ushort_t)0;
    }
    // build kT (swizzled) from k_lds
#pragma unroll
    for (int j = 0; j < 8; ++j) {
        const int e = j * 1024 + t * 4, r = e >> 8, c = e & 255;
#pragma unroll
        for (int x = 0; x < 4; ++x) {
            const int cc = c + x;
            const int sp = (r >> 3) ^ ((cc >> 1) & 3);
            kT_lds[cc * 32 + sp * 8 + (r & 7)] = k_lds[r * 264 + cc];
        }
    }
    __syncthreads();
    // export atfr (waves 0,1) and ktfr (all waves, 4 c-tiles each)
    if (wv < 2) {
        const u16x8 av = *(const u16x8*)&at_s[(wv * 16 + l16) * 40 + (quad << 3)];
        *(u16x8*)&atfr[(cb * 2 + wv) * 512 + lane * 8] = av;
    }
#pragma unroll
    for (int j2 = 0; j2 < 4; ++j2) {
        const int tc = wv * 4 + j2;
        const int c = tc * 16 + l16;
        const int sp = quad ^ ((c >> 1) & 3);
        *(u16x8*)&ktfr[(cb * 16 + tc) * 512 + lane * 8] = *(const u16x8*)&kT_lds[c * 32 + sp * 8];
    }
    // forward substitution: T[i] += sum_{j<i} A[i][j] T[j]
    for (int i = 1; i < 32; ++i) {
        if (t < 32) {
            float s = 0.f;
            for (int j = 0; j < i; ++j) s += Am[i * 33 + j] * Tm[j * 33 + t];
            Tm[i * 33 + t] += s;
        }
        __syncthreads();
    }
    // Tb = bf16(T * beta_col)
#pragma unroll
    for (int j = 0; j < 4; ++j) {
        const int e = j * 256 + t, i = e >> 5, jj = e & 31;
        Tb[i * 40 + jj] = f2bs(Tm[i * 33 + jj] * beta_s[jj]);
    }
    __syncthreads();
    // w = T'@k -> w_s (k_lds reuse); u = T'@v -> ufr (fragment layout direct)
    const bf16x8 tf = *(const bf16x8*)&Tb[(mi * 16 + l16) * 40 + (quad << 3)];
#pragma unroll
    for (int j = 0; j < 8; ++j) {
        const int nt = ni * 8 + j;
        const int d = (nt << 4) + l16;
        const int sp = quad ^ ((d >> 1) & 3);
        const bf16x8 kb = *(const bf16x8*)&kT_lds[d * 32 + (sp << 3)];
        const bf16x8 vb = *(const bf16x8*)&vT_lds[d * 32 + (sp << 3)];
        const f32x4 wacc = __builtin_amdgcn_mfma_f32_16x16x32_bf16(tf, kb, z4, 0, 0, 0);
        const f32x4 uacc = __builtin_amdgcn_mfma_f32_16x16x32_bf16(tf, vb, z4, 0, 0, 0);
        *(float4*)&ufr[((cb * 16 + nt) * 2 + mi) * 256 + lane * 4] =
            make_float4(uacc[0], uacc[1], uacc[2], uacc[3]);
#pragma unroll
        for (int r = 0; r < 4; ++r) {
            const int row = mi * 16 + (quad << 2) + r;
            k_lds[row * 264 + d] = f2bs(wacc[r]);  // w_s
        }
    }
    __syncthreads();
    // export wfr (waves 0,1)
    if (wv < 2) {
#pragma unroll
        for (int s = 0; s < 8; ++s) {
            const u16x8 wv8 = *(const u16x8*)&k_lds[(wv * 16 + l16) * 264 + s * 32 + (quad << 3)];
            *(u16x8*)&wfr[((cb * 2 + wv) * 8 + s) * 512 + lane * 8] = wv8;
        }
    }
}

// ---------------------- MFMA scan, single-wave-per-chain, LDS-streamed operands.
// One wave owns one (bh, dv-tile) chain. S master in 16 f32x4 regs. ALL large
// per-chunk operands (q, w, at, u) stream through double-buffered LDS via
// global_load_lds (no big register arrays -> no scratch spills, ~200 VGPR).
// kt goes global->reg at chunk head (consumed ~400cy later at S-update).
// Wait discipline: prologue vmcnt(0); per-chunk top vmcnt(8) (only the previous
// chunk's 8 dlt stores are younger than the current chunk's 36 staging DMAs).
__global__ __launch_bounds__(64, 1) void scan7_k(const ushort_t* __restrict__ qfr,
                                                 const ushort_t* __restrict__ wfr,
                                                 const float* __restrict__ ufr,
                                                 const ushort_t* __restrict__ atfr,
                                                 const ushort_t* __restrict__ ktfr,
                                                 float* __restrict__ dlt) {
    __shared__ ushort_t qstg[2][16 * 512];  // 32 KB
    __shared__ ushort_t wstg[2][16 * 512];  // 32 KB
    __shared__ ushort_t atstg[2][2 * 512];  // 4 KB
    __shared__ float ustg[2][2 * 256];      // 4 KB
    __shared__ ushort_t Sm[8 * 512];        // 8 KB  S mirror: slice s, unit l, 8 bf16
    __shared__ ushort_t uhL[512];           // 1 KB  uh B-frag
    const int l = threadIdx.x;
    const int q = l >> 4, c = l & 15;
    const int bh = blockIdx.x & 7, tile = blockIdx.x >> 3;
    const int b = bh >> 2, h = bh & 3;

    // zero the S mirror (read as S=0 for chunk 0)
    const int4 z16 = {0, 0, 0, 0};
#pragma unroll
    for (int e = 0; e < 8; ++e) *(int4*)&Sm[(e * 64 + l) * 8] = z16;

    f32x4 Sacc[16];
#pragma unroll
    for (int tc = 0; tc < 16; ++tc) {
        f32x4 z = {0.f, 0.f, 0.f, 0.f};
        Sacc[tc] = z;
    }

    // stage chunk ci's operands into LDS buffer p (36 gload16 total)
    auto stage = [&](int ci, int p) {
        const size_t cb = (size_t)(bh * NC + ci);
        const ushort_t* qsrc = qfr + cb * (16 * 512);
        const ushort_t* wsrc = wfr + cb * (16 * 512);
#pragma unroll
        for (int f = 0; f < 16; ++f) gload16(&qsrc[f * 512 + l * 8], &qstg[p][f * 512]);
#pragma unroll
        for (int f = 0; f < 16; ++f) gload16(&wsrc[f * 512 + l * 8], &wstg[p][f * 512]);
#pragma unroll
        for (int hf = 0; hf < 2; ++hf)
            gload16(&atfr[(cb * 2 + hf) * 512 + l * 8], &atstg[p][hf * 512]);
#pragma unroll
        for (int hf = 0; hf < 2; ++hf)
            gload16(&ufr[((cb * 16 + tile) * 2 + hf) * 256 + l * 4], &ustg[p][hf * 256]);
    };

    stage(0, 0);
    asm volatile("s_waitcnt vmcnt(0)" ::: "memory");
    __builtin_amdgcn_sched_barrier(0);

    for (int ci = 0; ci < NC; ++ci) {
        const int p = ci & 1;
        // current buffer's DMAs (issued one full chunk ago) must be complete; the
        // only younger vmem ops are the previous chunk's 8 dlt stores.
        asm volatile("s_waitcnt vmcnt(8)" ::: "memory");
        __builtin_amdgcn_sched_barrier(0);
        const size_t cb = (size_t)(bh * NC + ci);
        // kt for THIS chunk: global->reg, consumed at S-update (covered by compute)
        bf16x8 ktf[16];
        const ushort_t* ksrc = ktfr + cb * (16 * 512);
#pragma unroll
        for (int tc = 0; tc < 16; ++tc)
            ktf[tc] = *(const bf16x8*)&ksrc[tc * 512 + l * 8];
        // prefetch next chunk into the other buffer
        if (ci + 1 < NC) stage(ci + 1, p ^ 1);

        // ---- w@S (uh path) and q@S (output path), split even/odd k-slices
        f32x4 aw0[2], aw1[2], oq0[2], oq1[2];
#pragma unroll
        for (int hf = 0; hf < 2; ++hf) {
            f32x4 z = {0.f, 0.f, 0.f, 0.f};
            aw0[hf] = z; aw1[hf] = z; oq0[hf] = z; oq1[hf] = z;
        }
#pragma unroll
        for (int s = 0; s < 8; ++s) {
            const bf16x8 Sb = *(const bf16x8*)&Sm[(s * 64 + l) * 8];
            const bf16x8 w0 = *(const bf16x8*)&wstg[p][(0 * 8 + s) * 512 + l * 8];
            const bf16x8 w1 = *(const bf16x8*)&wstg[p][(1 * 8 + s) * 512 + l * 8];
            const bf16x8 q0 = *(const bf16x8*)&qstg[p][(0 * 8 + s) * 512 + l * 8];
            const bf16x8 q1 = *(const bf16x8*)&qstg[p][(1 * 8 + s) * 512 + l * 8];
            if (s & 1) {
                aw1[0] = __builtin_amdgcn_mfma_f32_16x16x32_bf16(w0, Sb, aw1[0], 0, 0, 0);
                aw1[1] = __builtin_amdgcn_mfma_f32_16x16x32_bf16(w1, Sb, aw1[1], 0, 0, 0);
                oq1[0] = __builtin_amdgcn_mfma_f32_16x16x32_bf16(q0, Sb, oq1[0], 0, 0, 0);
                oq1[1] = __builtin_amdgcn_mfma_f32_16x16x32_bf16(q1, Sb, oq1[1], 0, 0, 0);
            } else {
                aw0[0] = __builtin_amdgcn_mfma_f32_16x16x32_bf16(w0, Sb, aw0[0], 0, 0, 0);
                aw0[1] = __builtin_amdgcn_mfma_f32_16x16x32_bf16(w1, Sb, aw0[1], 0, 0, 0);
                oq0[0] = __builtin_amdgcn_mfma_f32_16x16x32_bf16(q0, Sb, oq0[0], 0, 0, 0);
                oq0[1] = __builtin_amdgcn_mfma_f32_16x16x32_bf16(q1, Sb, oq0[1], 0, 0, 0);
            }
        }
        // ---- uh = u - w@S -> bf16 B-frag via LDS (intra-wave round trip, no barrier)
#pragma unroll
        for (int hf = 0; hf < 2; ++hf) {
            const float4 uv = *(const float4*)&ustg[p][hf * 256 + l * 4];
            ushort4 up;
            up.x = f2bs(uv.x - aw0[hf][0] - aw1[hf][0]);
            up.y = f2bs(uv.y - aw0[hf][1] - aw1[hf][1]);
            up.z = f2bs(uv.z - aw0[hf][2] - aw1[hf][2]);
            up.w = f2bs(uv.w - aw0[hf][3] - aw1[hf][3]);
            *(ushort4*)&uhL[((2 * hf + (q >> 1)) * 16 + c) * 8 + (q & 1) * 4] = up;
        }
        const bf16x8 uhB = *(const bf16x8*)&uhL[l * 8];
        // ---- S update first (it feeds the next chunk's critical path)
#pragma unroll
        for (int tc = 0; tc < 16; ++tc) {
            Sacc[tc] = __builtin_amdgcn_mfma_f32_16x16x32_bf16(ktf[tc], uhB, Sacc[tc], 0, 0, 0);
            ushort4 pk;
            pk.x = f2bs(Sacc[tc][0]);
            pk.y = f2bs(Sacc[tc][1]);
            pk.z = f2bs(Sacc[tc][2]);
            pk.w = f2bs(Sacc[tc][3]);
            *(ushort4*)&Sm[(((tc >> 1) * 64) + ((tc & 1) * 2 + (q >> 1)) * 16 + c) * 8 +
                           (q & 1) * 4] = pk;
        }
        // ---- output o = q@S + attn@uh (off the serial path; overlaps mirror drain)
        const bf16x8 at0 = *(const bf16x8*)&atstg[p][0 * 512 + l * 8];
        const bf16x8 at1 = *(const bf16x8*)&atstg[p][1 * 512 + l * 8];
        oq0[0] = __builtin_amdgcn_mfma_f32_16x16x32_bf16(at0, uhB, oq0[0], 0, 0, 0);
        oq0[1] = __builtin_amdgcn_mfma_f32_16x16x32_bf16(at1, uhB, oq0[1], 0, 0, 0);
        const size_t gbase = ((size_t)(b * L_ + ci * 32)) * 1024 + (h << 8) + (tile << 4) + c;
#pragma unroll
        for (int hf = 0; hf < 2; ++hf)
#pragma unroll
            for (int r = 0; r < 4; ++r)
                dlt[gbase + (size_t)(hf * 16 + (q << 2) + r) * 1024] = oq0[hf][r] + oq1[hf][r];
    }
}

// ---------------- branch stats -> gate_in stat columns (bf16)
__global__ __launch_bounds__(64) void stats_k(const float* __restrict__ f1,
                                              const float* __restrict__ f3,
                                              const float* __restrict__ f7,
                                              const float* __restrict__ f31,
                                              const float* __restrict__ dl,
                                              const float* __restrict__ vv,
                                              ushort_t* __restrict__ gin) {
    const int row = blockIdx.x;  // (b*L+l)*H + h
    const int lane = threadIdx.x;
    const float* ptrs[6] = {f1, f3, f7, f31, dl, vv};
    const size_t base = (size_t)row * 256;
    ushort_t* gp = gin + (size_t)(row >> 2) * 1120 + 1024 + (row & 3) * 24;
    for (int br = 0; br < 6; ++br) {
        const float4 x = *(const float4*)&ptrs[br][base + lane * 4];
        float s1 = x.x + x.y + x.z + x.w;
        float s2 = x.x * x.x + x.y * x.y + x.z * x.z + x.w * x.w;
        float sa = fabsf(x.x) + fabsf(x.y) + fabsf(x.z) + fabsf(x.w);
        s1 = wred(s1); s2 = wred(s2); sa = wred(sa);
        if (lane == 0) {
            const float m = s1 / 256.f;
            float var = (s2 - 256.f * m * m) / 255.f;
            if (var < 0.f) var = 0.f;
            gp[br * 4 + 0] = f2bs(m);
            gp[br * 4 + 1] = f2bs(sqrtf(var));
            gp[br * 4 + 2] = f2bs(sa / 256.f);
            gp[br * 4 + 3] = f2bs(sqrtf(s2));
        }
    }
}

// ---------------------------------------------- logits -> softmax weights
__global__ __launch_bounds__(256) void wts_k(const float* __restrict__ hg,
                                             const float* __restrict__ w2,
                                             const float* __restrict__ b2,
                                             const float* __restrict__ glt,
                                             float* __restrict__ wts) {
    const int row = blockIdx.x;
    const int h = threadIdx.x >> 6, lane = threadIdx.x & 63;
    float hv[16];
    const float* hp = hg + (size_t)row * 1024;
#pragma unroll
    for (int ii = 0; ii < 16; ++ii) hv[ii] = hp[lane + 64 * ii];
    float lg[6];
#pragma unroll
    for (int s = 0; s < 6; ++s) {
        const int j = h * 6 + s;
        float acc = 0.f;
#pragma unroll
        for (int ii = 0; ii < 16; ++ii) acc += hv[ii] * w2[(size_t)(lane + 64 * ii) * 24 + j];
        lg[s] = wred(acc);
    }
    if (lane == 0) {
        const float temp = log1pf(expf(glt[h])) + 0.5f;
        float mx = -1e30f;
#pragma unroll
        for (int s = 0; s < 6; ++s) {
            lg[s] = (lg[s] + b2[h * 6 + s]) / temp;
            mx = fmaxf(mx, lg[s]);
        }
        float se = 0.f;
#pragma unroll
        for (int s = 0; s < 6; ++s) {
            lg[s] = expf(lg[s] - mx);
            se += lg[s];
        }
        float* o = &wts[(size_t)row * 24 + h * 6];
        const float inv = 1.f / se;
#pragma unroll
        for (int s = 0; s < 6; ++s) o[s] = lg[s] * inv;
    }
}

// -------------------------------------- fused = RMSNorm(sum ws*branch) * onorm_w (bf16 out)
__global__ __launch_bounds__(1024) void fuse_k(const float* __restrict__ f1,
                                               const float* __restrict__ f3,
                                               const float* __restrict__ f7,
                                               const float* __restrict__ f31,
                                               const float* __restrict__ dl,
                                               const float* __restrict__ vv,
                                               const float* __restrict__ wts,
                                               const float* __restrict__ onw,
                                               ushort_t* __restrict__ fused) {
    __shared__ float wloc[24];
    __shared__ float psum[16];
    const int row = blockIdx.x, t = threadIdx.x;
    if (t < 24) wloc[t] = wts[(size_t)row * 24 + t];
    __syncthreads();
    const int h = t >> 8, dd = t & 255;
    const size_t idx = (size_t)row * 1024 + t;
    const float* ptrs[6] = {f1, f3, f7, f31, dl, vv};
    float f = 0.f;
#pragma unroll
    for (int br = 0; br < 6; ++br) f += wloc[h * 6 + br] * ptrs[br][idx];
    float ss = wred(f * f);
    const int wave = t >> 6;
    if ((t & 63) == 0) psum[wave] = ss;
    __syncthreads();
    const float tot = psum[h * 4 + 0] + psum[h * 4 + 1] + psum[h * 4 + 2] + psum[h * 4 + 3];
    const float scale = rsqrtf(tot / 256.f + 1e-5f);
    fused[idx] = f2bs(f * scale * onw[dd]);
}

// ================================================================ launch
extern "C" void kernel_launch(void* const* d_in, const int* in_sizes, int n_in,
                              void* d_out, int out_size, void* d_ws, size_t ws_size,
                              hipStream_t stream) {
    const float* hs   = (const float*)d_in[0];
    const float* q_w  = (const float*)d_in[1];
    const float* k_w  = (const float*)d_in[2];
    const float* v_w  = (const float*)d_in[3];
    const float* b_w  = (const float*)d_in[4];
    const float* qc_w = (const float*)d_in[5];
    const float* kc_w = (const float*)d_in[6];
    const float* vc_w = (const float*)d_in[7];
    const float* f1w  = (const float*)d_in[8];
    const float* f3w  = (const float*)d_in[9];
    const float* f7w  = (const float*)d_in[10];
    const float* f31w = (const float*)d_in[11];
    const float* w1   = (const float*)d_in[12];
    const float* b1   = (const float*)d_in[13];
    const float* w2   = (const float*)d_in[14];
    const float* b2   = (const float*)d_in[15];
    const float* glt  = (const float*)d_in[16];
    const float* onw  = (const float*)d_in[17];
    const float* o_w  = (const float*)d_in[18];
    float* out = (float*)d_out;

    const size_t SZ = (size_t)B_ * L_ * D_;  // 4,194,304
    float* qlin = (float*)d_ws;       // qkv[4096][3072] spans 3*SZ; f1b after scan
    float* klin = qlin + SZ;          // ktfr+qfr bf16 [prep2..scan]; f3b after scan
    float* vlin = klin + SZ;          // f7b after scan
    float* qbuf = vlin + SZ;          // gin_bf (bf16) [beta_k .. gate gemm]
    float* kbuf = qbuf + SZ;          // kbf bf16 [conv..prep2]; hgate fp32; fused_bf
    float* vbuf = kbuf + SZ;          // v fp32 (silu)
    float* f31b = vbuf + SZ;          // qwT/kwT/vwT early; qbf bf16 [conv..prep2]; f31 after
    float* wb   = f31b + SZ;          // wfr bf16 [prep2..scan]; w1T after scan
    float* ub   = wb + SZ;            // ufr fp32 [prep2..scan]; owT after
    float* dlt  = ub + SZ;            // hs_bf early; dlt fp32 [scan..fuse]
    float* beta = dlt + SZ;
    float* attn = beta + (size_t)B_ * L_ * H_;   // atfr bf16
    float* f1b = qlin;
    float* f3b = klin;
    float* f7b = vlin;
    float* hgate = kbuf;
    float* qkv = qlin;  // [4096][3072]
    float* wts = attn + (size_t)B_ * H_ * NC * 1024;

    // bf16 aliases
    ushort_t* hs_bf = (ushort_t*)dlt;
    ushort_t* qwT = (ushort_t*)f31b;
    ushort_t* kwT = (ushort_t*)f31b + 1048576;
    ushort_t* vwT = (ushort_t*)f31b + 2097152;
    ushort_t* qbf = (ushort_t*)f31b + 3145728;
    ushort_t* kbf = (ushort_t*)kbuf;
    ushort_t* gin_bf = (ushort_t*)qbuf;
    ushort_t* w1T = (ushort_t*)(wb + 2359296);
    ushort_t* owT = (ushort_t*)ub;
    ushort_t* fused_bf = (ushort_t*)kbuf;
    ushort_t* ktfr = (ushort_t*)klin;            // SZ ushorts
    ushort_t* qfr = (ushort_t*)klin + SZ;        // second half of klin region
    ushort_t* wfr = (ushort_t*)wb;
    float* ufr = ub;
    ushort_t* atfr = (ushort_t*)attn;

    const int M = B_ * L_;  // 4096

    // weight transposes + activation cast
    tcast_k<<<dim3(32, 32), 256, 0, stream>>>(q_w, qwT, 1024, 1024);
    tcast_k<<<dim3(32, 32), 256, 0, stream>>>(k_w, kwT, 1024, 1024);
    tcast_k<<<dim3(32, 32), 256, 0, stream>>>(v_w, vwT, 1024, 1024);
    cast_k<<<4096, 256, 0, stream>>>(hs, hs_bf);
    // fused q|k|v projection: qkv[M][3072]
    gemm_bf<0><<<dim3(24, 32), 256, 0, stream>>>(hs_bf, qwT, nullptr, qkv, M, 3072, 1024);
    beta_k<<<M, 64, 0, stream>>>(hs, b_w, beta, gin_bf);
    // fused conv+silu(+l2norm): q,k emit bf16 only; v emits fp32
    convql_k<1, 0, 1><<<512, 256, 0, stream>>>(qkv + 0,    qc_w, nullptr, qbf);
    convql_k<1, 0, 1><<<512, 256, 0, stream>>>(qkv + 1024, kc_w, nullptr, kbf);
    convql_k<0, 1, 0><<<512, 256, 0, stream>>>(qkv + 2048, vc_w, vbuf, nullptr);
    // chunkwise delta rule
    prep2_k<<<B_ * H_ * NC, 256, 0, stream>>>(qbf, kbf, vbuf, beta, qfr, wfr, ufr, atfr, ktfr);
    scan7_k<<<128, 64, 0, stream>>>(qfr, wfr, ufr, atfr, ktfr, dlt);
    // fused FIR branches
    fir_k<<<512, 256, 0, stream>>>(vbuf, f1w, f3w, f7w, f31w, f1b, f3b, f7b, f31b);
    // gate
    stats_k<<<M * H_, 64, 0, stream>>>(f1b, f3b, f7b, f31b, dlt, vbuf, gin_bf);
    tcast_k<<<dim3(32, 35), 256, 0, stream>>>(w1, w1T, 1120, 1024);
    gemm_bf<1><<<dim3(8, 32), 256, 0, stream>>>(gin_bf, w1T, b1, hgate, M, 1024, 1120);
    wts_k<<<M, 256, 0, stream>>>(hgate, w2, b2, glt, wts);
    fuse_k<<<M, 1024, 0, stream>>>(f1b, f3b, f7b, f31b, dlt, vbuf, wts, onw, fused_bf);
    // output projection
    tcast_k<<<dim3(32, 32), 256, 0, stream>>>(o_w, owT, 1024, 1024);
    gemm_bf<0><<<dim3(8, 32), 256, 0, stream>>>(fused_bf, owT, nullptr, out, M, 1024, 1024);
}

// Round 4
// 564.859 us; speedup vs baseline: 1.0357x; 1.0357x over previous
//
#include <hip/hip_runtime.h>
#include <hip/hip_bf16.h>
#include <math.h>

#define B_ 2
#define L_ 2048
#define D_ 1024
#define H_ 4
#define NC 64   // chunks per sequence

typedef unsigned short ushort_t;
typedef __bf16 bf16x8 __attribute__((ext_vector_type(8)));
typedef float f32x4 __attribute__((ext_vector_type(4)));
typedef ushort_t u16x8 __attribute__((ext_vector_type(8)));
typedef short s16x8 __attribute__((ext_vector_type(8)));
typedef short s16x4 __attribute__((ext_vector_type(4)));

__device__ __forceinline__ ushort_t f2bs(float f) {
    __hip_bfloat16 h = __float2bfloat16(f);
    ushort_t u;
    __builtin_memcpy(&u, &h, 2);
    return u;
}

__device__ __forceinline__ float wred(float v) {
    v += __shfl_down(v, 32);
    v += __shfl_down(v, 16);
    v += __shfl_down(v, 8);
    v += __shfl_down(v, 4);
    v += __shfl_down(v, 2);
    v += __shfl_down(v, 1);
    return v;
}

__device__ __forceinline__ void gload16(const void* g, void* l) {
    __builtin_amdgcn_global_load_lds((const __attribute__((address_space(1))) void*)g,
                                     (__attribute__((address_space(3))) void*)l, 16, 0, 0);
}

// ---- lane-local fragment helpers (no asm, no exotic intrinsics) ----
// pack 4 f32 -> 4 bf16 (RNE via __float2bfloat16; compiler fuses to cvt_pk pairs)
__device__ __forceinline__ s16x4 pack4(float a, float b, float c, float d) {
    ushort4 u;
    u.x = f2bs(a); u.y = f2bs(b); u.z = f2bs(c); u.w = f2bs(d);
    return __builtin_bit_cast(s16x4, u);
}
// concat two K=16-half fragments into one K=32 operand (slot bijection
// sigma(quad,j) = quad*4+j (j<4) | 16+quad*4+(j-4) (j>=4); contraction is
// permutation-invariant as long as BOTH operands use sigma -- prep2's
// pair-packed exports do).
__device__ __forceinline__ bf16x8 cat8(s16x4 lo, s16x4 hi) {
    s16x8 r = __builtin_shufflevector(lo, hi, 0, 1, 2, 3, 4, 5, 6, 7);
    return __builtin_bit_cast(bf16x8, r);
}

// ------------------------------------------- transpose+cast: W[K][N] f32 -> WT[N][K] bf16
__global__ __launch_bounds__(256) void tcast_k(const float* __restrict__ W,
                                               ushort_t* __restrict__ WT, int K, int N) {
    __shared__ float tile[32 * 33];
    const int k0 = blockIdx.y << 5, n0 = blockIdx.x << 5;
    for (int e = threadIdx.x; e < 1024; e += 256)
        tile[(e >> 5) * 33 + (e & 31)] = W[(size_t)(k0 + (e >> 5)) * N + n0 + (e & 31)];
    __syncthreads();
    for (int e = threadIdx.x; e < 1024; e += 256)
        WT[(size_t)(n0 + (e >> 5)) * K + k0 + (e & 31)] = f2bs(tile[(e & 31) * 33 + (e >> 5)]);
}

// ------------------------------------------- cast f32 -> bf16 flat
__global__ __launch_bounds__(256) void cast_k(const float* __restrict__ x,
                                              ushort_t* __restrict__ y) {
    const int i = blockIdx.x * 256 + threadIdx.x;
    const float4 v = *(const float4*)&x[(size_t)i * 4];
    ushort4 p;
    p.x = f2bs(v.x); p.y = f2bs(v.y); p.z = f2bs(v.z); p.w = f2bs(v.w);
    *(ushort4*)&y[(size_t)i * 4] = p;
}

// ------------------------------------------- bf16 MFMA GEMM (TN): C = act(A @ Bt^T + bias)
template <int ACT>
__global__ __launch_bounds__(256) void gemm_bf(const ushort_t* __restrict__ A,
                                               const ushort_t* __restrict__ Bt,
                                               const float* __restrict__ bias,
                                               float* __restrict__ C,
                                               int M, int N, int K) {
    __shared__ ushort_t As[128 * 32];
    __shared__ ushort_t Bs[128 * 32];
    const int t = threadIdx.x;
    const int wv = t >> 6, l = t & 63;
    const int m0 = blockIdx.y << 7, n0 = blockIdx.x << 7;
    const int wm = wv & 1, wn = wv >> 1;
    const int q4 = l >> 4, c16 = l & 15;
    f32x4 acc[4][4];
#pragma unroll
    for (int i = 0; i < 4; ++i)
#pragma unroll
        for (int j = 0; j < 4; ++j) {
            f32x4 z = {0.f, 0.f, 0.f, 0.f};
            acc[i][j] = z;
        }
    const int srow = (l >> 2);
    const int scol = (l & 3) << 3;
    for (int k0 = 0; k0 < K; k0 += 32) {
        __syncthreads();
#pragma unroll
        for (int si = 0; si < 2; ++si) {
            const int s = wv * 2 + si;
            gload16(&A[(size_t)(m0 + s * 16 + srow) * K + k0 + scol], &As[s * 512]);
            gload16(&Bt[(size_t)(n0 + s * 16 + srow) * K + k0 + scol], &Bs[s * 512]);
        }
        __syncthreads();
        bf16x8 af[4], bff[4];
#pragma unroll
        for (int mi = 0; mi < 4; ++mi)
            af[mi] = *(const bf16x8*)&As[(wm * 64 + mi * 16 + c16) * 32 + q4 * 8];
#pragma unroll
        for (int ni = 0; ni < 4; ++ni)
            bff[ni] = *(const bf16x8*)&Bs[(wn * 64 + ni * 16 + c16) * 32 + q4 * 8];
#pragma unroll
        for (int mi = 0; mi < 4; ++mi)
#pragma unroll
            for (int ni = 0; ni < 4; ++ni)
                acc[mi][ni] = __builtin_amdgcn_mfma_f32_16x16x32_bf16(af[mi], bff[ni],
                                                                     acc[mi][ni], 0, 0, 0);
    }
#pragma unroll
    for (int mi = 0; mi < 4; ++mi)
#pragma unroll
        for (int ni = 0; ni < 4; ++ni)
#pragma unroll
            for (int r = 0; r < 4; ++r) {
                const int row = m0 + wm * 64 + mi * 16 + q4 * 4 + r;
                const int col = n0 + wn * 64 + ni * 16 + c16;
                float v = acc[mi][ni][r];
                if (ACT == 1) {
                    v += bias[col];
                    v = 0.5f * v * (1.0f + erff(v * 0.70710678118654752f));
                }
                C[(size_t)row * N + col] = v;
            }
}

// ---------------- fused causal conv(K=4) + silu (+ row l2norm), LDS-tiled
template <int DO_NORM, int EMIT_F32, int EMIT_BF>
__global__ __launch_bounds__(256) void convql_k(const float* __restrict__ X,
                                                const float* __restrict__ cw,
                                                float* __restrict__ Y,
                                                ushort_t* __restrict__ Ybf) {
    __shared__ float xs[35 * 256];
    const int bid = blockIdx.x;
    const int h = bid & 3, lt = (bid >> 2) & 63, b = bid >> 8;
    const int t = threadIdx.x;
    const int l0 = lt << 5;
    const int cg = (h << 8) | t;
    for (int e = t; e < 35 * 256; e += 256) {
        const int r = e >> 8, c = e & 255;
        const int gl = l0 + r - 3;
        xs[e] = (gl >= 0) ? X[((size_t)(b * L_) + gl) * 3072 + (h << 8) + c] : 0.f;
    }
    const float w0 = cw[cg * 4 + 0], w1 = cw[cg * 4 + 1];
    const float w2 = cw[cg * 4 + 2], w3 = cw[cg * 4 + 3];
    __syncthreads();
    float yr[32];
#pragma unroll
    for (int l = 0; l < 32; ++l) {
        const float a = xs[(l + 0) * 256 + t] * w0 + xs[(l + 1) * 256 + t] * w1 +
                        xs[(l + 2) * 256 + t] * w2 + xs[(l + 3) * 256 + t] * w3;
        yr[l] = a / (1.f + expf(-a));
    }
    if (DO_NORM) {
        __syncthreads();
#pragma unroll
        for (int l = 0; l < 32; ++l) xs[l * 256 + t] = yr[l];
        __syncthreads();
        const int wv = t >> 6, lane = t & 63;
#pragma unroll
        for (int ri = 0; ri < 8; ++ri) {
            const int r = wv * 8 + ri;
            float4 v = *(float4*)&xs[r * 256 + lane * 4];
            float ss = v.x * v.x + v.y * v.y + v.z * v.z + v.w * v.w;
            ss = wred(ss);
            ss = __shfl(ss, 0);
            const float s = rsqrtf(ss + 1e-6f);
            v.x *= s; v.y *= s; v.z *= s; v.w *= s;
            const size_t go = ((size_t)(b * L_) + l0 + r) * 1024 + (h << 8) + lane * 4;
            if (EMIT_F32) *(float4*)&Y[go] = v;
            if (EMIT_BF) {
                ushort4 p;
                p.x = f2bs(v.x); p.y = f2bs(v.y); p.z = f2bs(v.z); p.w = f2bs(v.w);
                *(ushort4*)&Ybf[go] = p;
            }
        }
    } else {
#pragma unroll
        for (int l = 0; l < 32; ++l)
            if (EMIT_F32) Y[((size_t)(b * L_) + l0 + l) * 1024 + cg] = yr[l];
    }
}

// ---------------- fused FIR branches (K=1,3,7,31), LDS-tiled, one read of v
__global__ __launch_bounds__(256) void fir_k(const float* __restrict__ V,
                                             const float* __restrict__ w1w,
                                             const float* __restrict__ w3w,
                                             const float* __restrict__ w7w,
                                             const float* __restrict__ w31w,
                                             float* __restrict__ o1,
                                             float* __restrict__ o3,
                                             float* __restrict__ o7,
                                             float* __restrict__ o31) {
    __shared__ float xs[62 * 256];
    const int bid = blockIdx.x;
    const int h = bid & 3, lt = (bid >> 2) & 63, b = bid >> 8;
    const int t = threadIdx.x;
    const int l0 = lt << 5;
    const int cg = (h << 8) | t;
    for (int e = t; e < 62 * 256; e += 256) {
        const int r = e >> 8, c = e & 255;
        const int gl = l0 + r - 30;
        xs[e] = (gl >= 0) ? V[((size_t)(b * L_) + gl) * 1024 + (h << 8) + c] : 0.f;
    }
    float lw31[31], lw7[7], lw3[3];
#pragma unroll
    for (int j = 0; j < 31; ++j) lw31[j] = w31w[cg * 31 + j];
#pragma unroll
    for (int j = 0; j < 7; ++j) lw7[j] = w7w[cg * 7 + j];
#pragma unroll
    for (int j = 0; j < 3; ++j) lw3[j] = w3w[cg * 3 + j];
    const float lw1 = w1w[cg];
    __syncthreads();
    for (int l = 0; l < 32; ++l) {
        float a31 = 0.f, a7 = 0.f, a3 = 0.f, v = 0.f;
#pragma unroll
        for (int j = 0; j < 31; ++j) {
            v = xs[(l + j) * 256 + t];
            a31 += v * lw31[j];
            if (j >= 24) a7 += v * lw7[j - 24];
            if (j >= 28) a3 += v * lw3[j - 28];
        }
        const size_t go = ((size_t)(b * L_) + l0 + l) * 1024 + cg;
        o31[go] = a31;
        o7[go] = a7;
        o3[go] = a3;
        o1[go] = v * lw1;
    }
}

// ------------------- beta = sigmoid(hs @ b_w); also emit gate_in hs-part (bf16)
__global__ __launch_bounds__(64) void beta_k(const float* __restrict__ hs,
                                             const float* __restrict__ bw,
                                             float* __restrict__ beta,
                                             ushort_t* __restrict__ gin) {
    const int row = blockIdx.x;
    const int lane = threadIdx.x;
    float a0 = 0, a1 = 0, a2 = 0, a3 = 0;
    const float* hp = hs + (size_t)row * D_;
    ushort_t* gp = gin + (size_t)row * 1120;
    for (int c = lane; c < D_; c += 64) {
        const float x = hp[c];
        gp[c] = f2bs(x);
        a0 += x * bw[c * 4 + 0];
        a1 += x * bw[c * 4 + 1];
        a2 += x * bw[c * 4 + 2];
        a3 += x * bw[c * 4 + 3];
    }
    a0 = wred(a0); a1 = wred(a1); a2 = wred(a2); a3 = wred(a3);
    if (lane == 0) {
        float* o = beta + (size_t)row * 4;
        o[0] = 1.f / (1.f + expf(-a0));
        o[1] = 1.f / (1.f + expf(-a1));
        o[2] = 1.f / (1.f + expf(-a2));
        o[3] = 1.f / (1.f + expf(-a3));
    }
}

// --------------- fused MFMA delta-prep. Exports scan operands as K=16 A-frag
// PAIRS (two k-16-tiles per 16B lane unit, frag-linear):
//   qfr/wfr[((cb*2+half)*8+sp)*512 + lane*8]  : [k=sp*32+quad*4..| +16..]
//   atfr[(cb*2+half)*512 + lane*8]            : attn row-half, khalf pair
//   ktfr[(cb*16+tc)*512 + lane*8]             : kT tile tc, khalf pair
//   ufr[((cb*16+nt)*2+mi)*256 + lane*4]       : fp32 C-layout slices
__global__ __launch_bounds__(256) void prep2_k(const ushort_t* __restrict__ qbf,
                                               const ushort_t* __restrict__ kbf,
                                               const float* __restrict__ vg,
                                               const float* __restrict__ beta,
                                               ushort_t* __restrict__ qfr,
                                               ushort_t* __restrict__ wfr,
                                               float* __restrict__ ufr,
                                               ushort_t* __restrict__ atfr,
                                               ushort_t* __restrict__ ktfr) {
    __shared__ ushort_t k_lds[32 * 264];   // k rows; reused as w_s later
    __shared__ ushort_t kT_lds[256 * 32];  // swizzled: seg s at (s ^ ((c>>1)&3))
    __shared__ ushort_t vT_lds[256 * 32];  // same swizzle
    __shared__ float Am[32 * 33];
    __shared__ float Tm[32 * 33];
    __shared__ ushort_t Tb[32 * 40];       // T' bf16
    __shared__ ushort_t at_s[32 * 40];     // attn bf16 (row-major, 16B-aligned rows)
    __shared__ float beta_s[32];
    const int bid = blockIdx.x;  // bh*NC + ci
    const int bh = bid >> 6, ci = bid & 63;
    const int b = bh >> 2, h = bh & 3;
    const int t = threadIdx.x;
    const int wv = t >> 6, lane = t & 63;
    const int mi = wv & 1, ni = wv >> 1;
    const int l16 = lane & 15, quad = lane >> 4;
    const size_t cb = (size_t)bid;
    const size_t grow = ((size_t)(b * L_ + ci * 32)) * 1024 + (h << 8);
    const f32x4 z4 = {0.f, 0.f, 0.f, 0.f};

    if (t < 32) beta_s[t] = beta[(size_t)(b * L_ + ci * 32 + t) * 4 + h];
    // stage k rows (plain, padded)
#pragma unroll
    for (int j = 0; j < 4; ++j) {
        const int idx = j * 2048 + t * 8, r = idx >> 8, c = idx & 255;
        *(u16x8*)&k_lds[r * 264 + c] = *(const u16x8*)&kbf[grow + (size_t)r * 1024 + c];
    }
    // build vT (bf16, swizzled) from global v
#pragma unroll
    for (int j = 0; j < 8; ++j) {
        const int e = j * 1024 + t * 4, r = e >> 8, c = e & 255;
        const float4 v4 = *(const float4*)&vg[grow + (size_t)r * 1024 + c];
        const float vv[4] = {v4.x, v4.y, v4.z, v4.w};
#pragma unroll
        for (int x = 0; x < 4; ++x) {
            const int cc = c + x;
            const int sp = (r >> 3) ^ ((cc >> 1) & 3);
            vT_lds[cc * 32 + sp * 8 + (r & 7)] = f2bs(vv[x]);
        }
    }
    // G = k@kT and attn = q@kT from global register fragments; waves 0,1 export qfr
    f32x4 g = z4, atv = z4;
#pragma unroll
    for (int s = 0; s < 8; ++s) {
        const bf16x8 a =
            *(const bf16x8*)&kbf[grow + (size_t)(mi * 16 + l16) * 1024 + s * 32 + (quad << 3)];
        const bf16x8 bb =
            *(const bf16x8*)&kbf[grow + (size_t)(ni * 16 + l16) * 1024 + s * 32 + (quad << 3)];
        const bf16x8 qa =
            *(const bf16x8*)&qbf[grow + (size_t)(mi * 16 + l16) * 1024 + s * 32 + (quad << 3)];
        g = __builtin_amdgcn_mfma_f32_16x16x32_bf16(a, bb, g, 0, 0, 0);
        atv = __builtin_amdgcn_mfma_f32_16x16x32_bf16(qa, bb, atv, 0, 0, 0);
        if (ni == 0) {  // K=16 pair-packed export (lane: k=s*32+quad*4.. | +16..)
            const size_t ga = grow + (size_t)(mi * 16 + l16) * 1024 + s * 32 + (quad << 2);
            const ushort4 q0 = *(const ushort4*)&qbf[ga];
            const ushort4 q1 = *(const ushort4*)&qbf[ga + 16];
            ushort_t* qd = &qfr[((cb * 2 + mi) * 8 + s) * 512 + lane * 8];
            *(ushort4*)qd = q0;
            *(ushort4*)(qd + 4) = q1;
        }
    }
    __syncthreads();  // beta_s + k_lds + vT visible
    // Am / Tm init + attn -> at_s
#pragma unroll
    for (int r = 0; r < 4; ++r) {
        const int row = mi * 16 + (quad << 2) + r;
        const int col = ni * 16 + l16;
        Am[row * 33 + col] = (col < row) ? -beta_s[row] * g[r] : 0.f;
        Tm[row * 33 + col] = (row == col) ? 1.f : 0.f;
        at_s[row * 40 + col] = (col <= row) ? f2bs(atv[r]) : (ushort_t)0;
    }
    // build kT (swizzled) from k_lds
#pragma unroll
    for (int j = 0; j < 8; ++j) {
        const int e = j * 1024 + t * 4, r = e >> 8, c = e & 255;
#pragma unroll
        for (int x = 0; x < 4; ++x) {
            const int cc = c + x;
            const int sp = (r >> 3) ^ ((cc >> 1) & 3);
            kT_lds[cc * 32 + sp * 8 + (r & 7)] = k_lds[r * 264 + cc];
        }
    }
    __syncthreads();
    // export atfr (waves 0,1): khalf-pair per lane
    if (wv < 2) {
        const int ra = (wv * 16 + l16) * 40 + (quad << 2);
        const ushort4 a0 = *(const ushort4*)&at_s[ra];
        const ushort4 a1 = *(const ushort4*)&at_s[ra + 16];
        ushort_t* ad = &atfr[(cb * 2 + wv) * 512 + lane * 8];
        *(ushort4*)ad = a0;
        *(ushort4*)(ad + 4) = a1;
    }
    // export ktfr (all waves, 4 c-tiles each): lane holds kT[d][khalf*16+quad*4+j]
#pragma unroll
    for (int j2 = 0; j2 < 4; ++j2) {
        const int tc = wv * 4 + j2;
        const int d = tc * 16 + l16;
        const int x = (d >> 1) & 3;
        const int base = d * 32 + ((quad & 1) << 2);
        const ushort4 k0 = *(const ushort4*)&kT_lds[base + ((((quad >> 1) + 0) ^ x) << 3)];
        const ushort4 k1 = *(const ushort4*)&kT_lds[base + ((((quad >> 1) + 2) ^ x) << 3)];
        ushort_t* kd = &ktfr[(cb * 16 + tc) * 512 + lane * 8];
        *(ushort4*)kd = k0;
        *(ushort4*)(kd + 4) = k1;
    }
    // forward substitution: T[i] += sum_{j<i} A[i][j] T[j]
    for (int i = 1; i < 32; ++i) {
        if (t < 32) {
            float s = 0.f;
            for (int j = 0; j < i; ++j) s += Am[i * 33 + j] * Tm[j * 33 + t];
            Tm[i * 33 + t] += s;
        }
        __syncthreads();
    }
    // Tb = bf16(T * beta_col)
#pragma unroll
    for (int j = 0; j < 4; ++j) {
        const int e = j * 256 + t, i = e >> 5, jj = e & 31;
        Tb[i * 40 + jj] = f2bs(Tm[i * 33 + jj] * beta_s[jj]);
    }
    __syncthreads();
    // w = T'@k -> w_s (k_lds reuse); u = T'@v -> ufr (fragment layout direct)
    const bf16x8 tf = *(const bf16x8*)&Tb[(mi * 16 + l16) * 40 + (quad << 3)];
#pragma unroll
    for (int j = 0; j < 8; ++j) {
        const int nt = ni * 8 + j;
        const int d = (nt << 4) + l16;
        const int sp = quad ^ ((d >> 1) & 3);
        const bf16x8 kb = *(const bf16x8*)&kT_lds[d * 32 + (sp << 3)];
        const bf16x8 vb = *(const bf16x8*)&vT_lds[d * 32 + (sp << 3)];
        const f32x4 wacc = __builtin_amdgcn_mfma_f32_16x16x32_bf16(tf, kb, z4, 0, 0, 0);
        const f32x4 uacc = __builtin_amdgcn_mfma_f32_16x16x32_bf16(tf, vb, z4, 0, 0, 0);
        *(float4*)&ufr[((cb * 16 + nt) * 2 + mi) * 256 + lane * 4] =
            make_float4(uacc[0], uacc[1], uacc[2], uacc[3]);
#pragma unroll
        for (int r = 0; r < 4; ++r) {
            const int row = mi * 16 + (quad << 2) + r;
            k_lds[row * 264 + d] = f2bs(wacc[r]);  // w_s
        }
    }
    __syncthreads();
    // export wfr (waves 0,1): K=16 pair-packed like qfr
    if (wv < 2) {
#pragma unroll
        for (int sp = 0; sp < 8; ++sp) {
            const int rb = (wv * 16 + l16) * 264 + sp * 32 + (quad << 2);
            const ushort4 w0 = *(const ushort4*)&k_lds[rb];
            const ushort4 w1 = *(const ushort4*)&k_lds[rb + 16];
            ushort_t* wd = &wfr[((cb * 2 + wv) * 8 + sp) * 512 + lane * 8];
            *(ushort4*)wd = w0;
            *(ushort4*)(wd + 4) = w1;
        }
    }
}

// ---------------------- MFMA scan, lane-local edition (K=32, pair-packed).
// One wave owns one (bh, dv-tile) chain. S (and uh) live as f32 C-layout
// accumulators; their bf16 MFMA-B operands are built LANE-LOCALLY: C-layout
// row-mapping (quad*4+r) equals the K=16-half B k-mapping, and a 16x16x32 MFMA
// contracts slot-pairwise, so pair-packed A-frags (from prep2) against
// cat8(frag_lo, frag_hi) B-operands compute the exact K=32 product under the
// slot bijection sigma. No LDS round trip, no barriers on the serial path.
// q/w/at/u stream through double-buffered LDS via global_load_lds; kt is
// double-buffered in macro-named register arrays (static indexing, SROA-safe).
__global__ __launch_bounds__(64, 1) void scan9_k(const ushort_t* __restrict__ qfr,
                                                 const ushort_t* __restrict__ wfr,
                                                 const float* __restrict__ ufr,
                                                 const ushort_t* __restrict__ atfr,
                                                 const ushort_t* __restrict__ ktfr,
                                                 float* __restrict__ dlt) {
    __shared__ ushort_t qstg[2][16 * 512];  // 32 KB
    __shared__ ushort_t wstg[2][16 * 512];  // 32 KB
    __shared__ ushort_t atstg[2][2 * 512];  // 4 KB
    __shared__ float ustg[2][2 * 256];      // 4 KB
    const int l = threadIdx.x;
    const int qd = l >> 4, c = l & 15;
    const int bh = blockIdx.x & 7, tile = blockIdx.x >> 3;
    const int b = bh >> 2, h = bh & 3;

    f32x4 Sacc[16];
    s16x4 SB[16];
#pragma unroll
    for (int tc = 0; tc < 16; ++tc) {
        f32x4 z = {0.f, 0.f, 0.f, 0.f};
        Sacc[tc] = z;
        s16x4 zs = {0, 0, 0, 0};
        SB[tc] = zs;
    }
    s16x8 ktA[16], ktB[16];

    auto stage = [&](int ci, int p) {
        const size_t cb = (size_t)(bh * NC + ci);
        const ushort_t* qsrc = qfr + cb * (16 * 512);
        const ushort_t* wsrc = wfr + cb * (16 * 512);
#pragma unroll
        for (int f = 0; f < 16; ++f) gload16(&qsrc[f * 512 + l * 8], &qstg[p][f * 512]);
#pragma unroll
        for (int f = 0; f < 16; ++f) gload16(&wsrc[f * 512 + l * 8], &wstg[p][f * 512]);
#pragma unroll
        for (int hf = 0; hf < 2; ++hf)
            gload16(&atfr[(cb * 2 + hf) * 512 + l * 8], &atstg[p][hf * 512]);
#pragma unroll
        for (int hf = 0; hf < 2; ++hf)
            gload16(&ufr[((cb * 16 + tile) * 2 + hf) * 256 + l * 4], &ustg[p][hf * 256]);
    };

    // prologue: kt(0) -> ktA; stage(0) -> buf0; drain
    {
        const ushort_t* ksrc = ktfr + (size_t)(bh * NC) * (16 * 512);
#pragma unroll
        for (int tc = 0; tc < 16; ++tc) ktA[tc] = *(const s16x8*)&ksrc[tc * 512 + l * 8];
    }
    stage(0, 0);
    asm volatile("s_waitcnt vmcnt(0)" ::: "memory");
    __builtin_amdgcn_sched_barrier(0);

// per-chunk body. KT = current kt regs (array NAME), KTN = next (prefetch target).
// vmcnt(8): buf P's 36 DMAs (issued one chunk ago) must be done; only the
// previous chunk's 8 dlt stores may remain in flight.
#define SC_BODY(CI, P, KT, KTN)                                                              \
    {                                                                                        \
        asm volatile("s_waitcnt vmcnt(8)" ::: "memory");                                     \
        __builtin_amdgcn_sched_barrier(0);                                                   \
        if ((CI) + 1 < NC) {                                                                 \
            const ushort_t* ksrc = ktfr + (size_t)(bh * NC + (CI) + 1) * (16 * 512);         \
            _Pragma("unroll") for (int tc = 0; tc < 16; ++tc)                                \
                KTN[tc] = *(const s16x8*)&ksrc[tc * 512 + l * 8];                            \
            stage((CI) + 1, (P) ^ 1);                                                        \
        }                                                                                    \
        f32x4 aw[2], oq[2];                                                                  \
        _Pragma("unroll") for (int hf = 0; hf < 2; ++hf) {                                   \
            f32x4 z = {0.f, 0.f, 0.f, 0.f};                                                  \
            aw[hf] = z;                                                                      \
            oq[hf] = z;                                                                      \
        }                                                                                    \
        _Pragma("unroll") for (int sp = 0; sp < 8; ++sp) {                                   \
            const bf16x8 Sop = cat8(SB[2 * sp + 0], SB[2 * sp + 1]);                         \
            _Pragma("unroll") for (int hf = 0; hf < 2; ++hf) {                               \
                const bf16x8 wv8 = *(const bf16x8*)&wstg[P][(hf * 8 + sp) * 512 + l * 8];    \
                const bf16x8 qv8 = *(const bf16x8*)&qstg[P][(hf * 8 + sp) * 512 + l * 8];    \
                aw[hf] = __builtin_amdgcn_mfma_f32_16x16x32_bf16(wv8, Sop, aw[hf], 0, 0, 0); \
                oq[hf] = __builtin_amdgcn_mfma_f32_16x16x32_bf16(qv8, Sop, oq[hf], 0, 0, 0); \
            }                                                                                \
        }                                                                                    \
        s16x4 uhB[2];                                                                        \
        _Pragma("unroll") for (int hf = 0; hf < 2; ++hf) {                                   \
            const float4 uv = *(const float4*)&ustg[P][hf * 256 + l * 4];                    \
            uhB[hf] = pack4(uv.x - aw[hf][0], uv.y - aw[hf][1],                              \
                            uv.z - aw[hf][2], uv.w - aw[hf][3]);                             \
        }                                                                                    \
        const bf16x8 Uop = cat8(uhB[0], uhB[1]);                                             \
        _Pragma("unroll") for (int tc = 0; tc < 16; ++tc) {                                  \
            Sacc[tc] = __builtin_amdgcn_mfma_f32_16x16x32_bf16(                              \
                __builtin_bit_cast(bf16x8, KT[tc]), Uop, Sacc[tc], 0, 0, 0);                 \
            SB[tc] = pack4(Sacc[tc][0], Sacc[tc][1], Sacc[tc][2], Sacc[tc][3]);              \
        }                                                                                    \
        _Pragma("unroll") for (int hf = 0; hf < 2; ++hf) {                                   \
            const bf16x8 av = *(const bf16x8*)&atstg[P][hf * 512 + l * 8];                   \
            oq[hf] = __builtin_amdgcn_mfma_f32_16x16x32_bf16(av, Uop, oq[hf], 0, 0, 0);      \
        }                                                                                    \
        const size_t gbase =                                                                 \
            ((size_t)(b * L_ + (CI) * 32)) * 1024 + (h << 8) + (tile << 4) + c;              \
        _Pragma("unroll") for (int hf = 0; hf < 2; ++hf)                                     \
            _Pragma("unroll") for (int r = 0; r < 4; ++r)                                    \
                dlt[gbase + (size_t)(hf * 16 + (qd << 2) + r) * 1024] = oq[hf][r];           \
    }

    for (int ci = 0; ci < NC; ci += 2) {
        SC_BODY(ci, 0, ktA, ktB)
        SC_BODY(ci + 1, 1, ktB, ktA)
    }
#undef SC_BODY
}

// ---------------- branch stats -> gate_in stat columns (bf16)
__global__ __launch_bounds__(64) void stats_k(const float* __restrict__ f1,
                                              const float* __restrict__ f3,
                                              const float* __restrict__ f7,
                                              const float* __restrict__ f31,
                                              const float* __restrict__ dl,
                                              const float* __restrict__ vv,
                                              ushort_t* __restrict__ gin) {
    const int row = blockIdx.x;  // (b*L+l)*H + h
    const int lane = threadIdx.x;
    const float* ptrs[6] = {f1, f3, f7, f31, dl, vv};
    const size_t base = (size_t)row * 256;
    ushort_t* gp = gin + (size_t)(row >> 2) * 1120 + 1024 + (row & 3) * 24;
    for (int br = 0; br < 6; ++br) {
        const float4 x = *(const float4*)&ptrs[br][base + lane * 4];
        float s1 = x.x + x.y + x.z + x.w;
        float s2 = x.x * x.x + x.y * x.y + x.z * x.z + x.w * x.w;
        float sa = fabsf(x.x) + fabsf(x.y) + fabsf(x.z) + fabsf(x.w);
        s1 = wred(s1); s2 = wred(s2); sa = wred(sa);
        if (lane == 0) {
            const float m = s1 / 256.f;
            float var = (s2 - 256.f * m * m) / 255.f;
            if (var < 0.f) var = 0.f;
            gp[br * 4 + 0] = f2bs(m);
            gp[br * 4 + 1] = f2bs(sqrtf(var));
            gp[br * 4 + 2] = f2bs(sa / 256.f);
            gp[br * 4 + 3] = f2bs(sqrtf(s2));
        }
    }
}

// ---------------------------------------------- logits -> softmax weights
__global__ __launch_bounds__(256) void wts_k(const float* __restrict__ hg,
                                             const float* __restrict__ w2,
                                             const float* __restrict__ b2,
                                             const float* __restrict__ glt,
                                             float* __restrict__ wts) {
    const int row = blockIdx.x;
    const int h = threadIdx.x >> 6, lane = threadIdx.x & 63;
    float hv[16];
    const float* hp = hg + (size_t)row * 1024;
#pragma unroll
    for (int ii = 0; ii < 16; ++ii) hv[ii] = hp[lane + 64 * ii];
    float lg[6];
#pragma unroll
    for (int s = 0; s < 6; ++s) {
        const int j = h * 6 + s;
        float acc = 0.f;
#pragma unroll
        for (int ii = 0; ii < 16; ++ii) acc += hv[ii] * w2[(size_t)(lane + 64 * ii) * 24 + j];
        lg[s] = wred(acc);
    }
    if (lane == 0) {
        const float temp = log1pf(expf(glt[h])) + 0.5f;
        float mx = -1e30f;
#pragma unroll
        for (int s = 0; s < 6; ++s) {
            lg[s] = (lg[s] + b2[h * 6 + s]) / temp;
            mx = fmaxf(mx, lg[s]);
        }
        float se = 0.f;
#pragma unroll
        for (int s = 0; s < 6; ++s) {
            lg[s] = expf(lg[s] - mx);
            se += lg[s];
        }
        float* o = &wts[(size_t)row * 24 + h * 6];
        const float inv = 1.f / se;
#pragma unroll
        for (int s = 0; s < 6; ++s) o[s] = lg[s] * inv;
    }
}

// -------------------------------------- fused = RMSNorm(sum ws*branch) * onorm_w (bf16 out)
__global__ __launch_bounds__(1024) void fuse_k(const float* __restrict__ f1,
                                               const float* __restrict__ f3,
                                               const float* __restrict__ f7,
                                               const float* __restrict__ f31,
                                               const float* __restrict__ dl,
                                               const float* __restrict__ vv,
                                               const float* __restrict__ wts,
                                               const float* __restrict__ onw,
                                               ushort_t* __restrict__ fused) {
    __shared__ float wloc[24];
    __shared__ float psum[16];
    const int row = blockIdx.x, t = threadIdx.x;
    if (t < 24) wloc[t] = wts[(size_t)row * 24 + t];
    __syncthreads();
    const int h = t >> 8, dd = t & 255;
    const size_t idx = (size_t)row * 1024 + t;
    const float* ptrs[6] = {f1, f3, f7, f31, dl, vv};
    float f = 0.f;
#pragma unroll
    for (int br = 0; br < 6; ++br) f += wloc[h * 6 + br] * ptrs[br][idx];
    float ss = wred(f * f);
    const int wave = t >> 6;
    if ((t & 63) == 0) psum[wave] = ss;
    __syncthreads();
    const float tot = psum[h * 4 + 0] + psum[h * 4 + 1] + psum[h * 4 + 2] + psum[h * 4 + 3];
    const float scale = rsqrtf(tot / 256.f + 1e-5f);
    fused[idx] = f2bs(f * scale * onw[dd]);
}

// ================================================================ launch
extern "C" void kernel_launch(void* const* d_in, const int* in_sizes, int n_in,
                              void* d_out, int out_size, void* d_ws, size_t ws_size,
                              hipStream_t stream) {
    const float* hs   = (const float*)d_in[0];
    const float* q_w  = (const float*)d_in[1];
    const float* k_w  = (const float*)d_in[2];
    const float* v_w  = (const float*)d_in[3];
    const float* b_w  = (const float*)d_in[4];
    const float* qc_w = (const float*)d_in[5];
    const float* kc_w = (const float*)d_in[6];
    const float* vc_w = (const float*)d_in[7];
    const float* f1w  = (const float*)d_in[8];
    const float* f3w  = (const float*)d_in[9];
    const float* f7w  = (const float*)d_in[10];
    const float* f31w = (const float*)d_in[11];
    const float* w1   = (const float*)d_in[12];
    const float* b1   = (const float*)d_in[13];
    const float* w2   = (const float*)d_in[14];
    const float* b2   = (const float*)d_in[15];
    const float* glt  = (const float*)d_in[16];
    const float* onw  = (const float*)d_in[17];
    const float* o_w  = (const float*)d_in[18];
    float* out = (float*)d_out;

    const size_t SZ = (size_t)B_ * L_ * D_;  // 4,194,304
    float* qlin = (float*)d_ws;       // qkv[4096][3072] spans 3*SZ; f1b after scan
    float* klin = qlin + SZ;          // ktfr+qfr bf16 [prep2..scan]; f3b after scan
    float* vlin = klin + SZ;          // f7b after scan
    float* qbuf = vlin + SZ;          // gin_bf (bf16) [beta_k .. gate gemm]
    float* kbuf = qbuf + SZ;          // kbf bf16 [conv..prep2]; hgate fp32; fused_bf
    float* vbuf = kbuf + SZ;          // v fp32 (silu)
    float* f31b = vbuf + SZ;          // qwT/kwT/vwT early; qbf bf16 [conv..prep2]; f31 after
    float* wb   = f31b + SZ;          // wfr bf16 [prep2..scan]; w1T after scan
    float* ub   = wb + SZ;            // ufr fp32 [prep2..scan]; owT after
    float* dlt  = ub + SZ;            // hs_bf early; dlt fp32 [scan..fuse]
    float* beta = dlt + SZ;
    float* attn = beta + (size_t)B_ * L_ * H_;   // atfr bf16
    float* f1b = qlin;
    float* f3b = klin;
    float* f7b = vlin;
    float* hgate = kbuf;
    float* qkv = qlin;  // [4096][3072]
    float* wts = attn + (size_t)B_ * H_ * NC * 1024;

    // bf16 aliases
    ushort_t* hs_bf = (ushort_t*)dlt;
    ushort_t* qwT = (ushort_t*)f31b;
    ushort_t* kwT = (ushort_t*)f31b + 1048576;
    ushort_t* vwT = (ushort_t*)f31b + 2097152;
    ushort_t* qbf = (ushort_t*)f31b + 3145728;
    ushort_t* kbf = (ushort_t*)kbuf;
    ushort_t* gin_bf = (ushort_t*)qbuf;
    ushort_t* w1T = (ushort_t*)(wb + 2359296);
    ushort_t* owT = (ushort_t*)ub;
    ushort_t* fused_bf = (ushort_t*)kbuf;
    ushort_t* ktfr = (ushort_t*)klin;            // SZ ushorts
    ushort_t* qfr = (ushort_t*)klin + SZ;        // second half of klin region
    ushort_t* wfr = (ushort_t*)wb;
    float* ufr = ub;
    ushort_t* atfr = (ushort_t*)attn;

    const int M = B_ * L_;  // 4096

    // weight transposes + activation cast
    tcast_k<<<dim3(32, 32), 256, 0, stream>>>(q_w, qwT, 1024, 1024);
    tcast_k<<<dim3(32, 32), 256, 0, stream>>>(k_w, kwT, 1024, 1024);
    tcast_k<<<dim3(32, 32), 256, 0, stream>>>(v_w, vwT, 1024, 1024);
    cast_k<<<4096, 256, 0, stream>>>(hs, hs_bf);
    // fused q|k|v projection: qkv[M][3072]
    gemm_bf<0><<<dim3(24, 32), 256, 0, stream>>>(hs_bf, qwT, nullptr, qkv, M, 3072, 1024);
    beta_k<<<M, 64, 0, stream>>>(hs, b_w, beta, gin_bf);
    // fused conv+silu(+l2norm): q,k emit bf16 only; v emits fp32
    convql_k<1, 0, 1><<<512, 256, 0, stream>>>(qkv + 0,    qc_w, nullptr, qbf);
    convql_k<1, 0, 1><<<512, 256, 0, stream>>>(qkv + 1024, kc_w, nullptr, kbf);
    convql_k<0, 1, 0><<<512, 256, 0, stream>>>(qkv + 2048, vc_w, vbuf, nullptr);
    // chunkwise delta rule
    prep2_k<<<B_ * H_ * NC, 256, 0, stream>>>(qbf, kbf, vbuf, beta, qfr, wfr, ufr, atfr, ktfr);
    scan9_k<<<128, 64, 0, stream>>>(qfr, wfr, ufr, atfr, ktfr, dlt);
    // fused FIR branches
    fir_k<<<512, 256, 0, stream>>>(vbuf, f1w, f3w, f7w, f31w, f1b, f3b, f7b, f31b);
    // gate
    stats_k<<<M * H_, 64, 0, stream>>>(f1b, f3b, f7b, f31b, dlt, vbuf, gin_bf);
    tcast_k<<<dim3(32, 35), 256, 0, stream>>>(w1, w1T, 1120, 1024);
    gemm_bf<1><<<dim3(8, 32), 256, 0, stream>>>(gin_bf, w1T, b1, hgate, M, 1024, 1120);
    wts_k<<<M, 256, 0, stream>>>(hgate, w2, b2, glt, wts);
    fuse_k<<<M, 1024, 0, stream>>>(f1b, f3b, f7b, f31b, dlt, vbuf, wts, onw, fused_bf);
    // output projection
    tcast_k<<<dim3(32, 32), 256, 0, stream>>>(o_w, owT, 1024, 1024);
    gemm_bf<0><<<dim3(8, 32), 256, 0, stream>>>(fused_bf, owT, nullptr, out, M, 1024, 1024);
}